// Round 1
// baseline (5374.359 us; speedup 1.0000x reference)
//
#include <hip/hip_runtime.h>
#include <math.h>

#define H 43
#define H3 129
#define NN 100000
#define NE 1600000
#define NG 2048
#define FFD 392
#define NLB 138

// ---------------- m = h @ W  ([N,43] @ [43,43]) ----------------
__global__ void mm_hW(const float* __restrict__ h, const float* __restrict__ W,
                      float* __restrict__ m, int n_total) {
    __shared__ float Ws[H * H];
    for (int i = threadIdx.x; i < H * H; i += blockDim.x) Ws[i] = W[i];
    __syncthreads();
    int t = blockIdx.x * blockDim.x + threadIdx.x;
    if (t >= n_total) return;
    int n = t / H, j = t % H;
    const float* hr = h + n * H;
    float acc = 0.f;
#pragma unroll
    for (int k = 0; k < H; ++k) acc += hr[k] * Ws[k * H + j];
    m[t] = acc;
}

// ---------------- agg[dst] += m[src] over edges ----------------
__global__ void scatter_add(const float* __restrict__ m, const int* __restrict__ src,
                            const int* __restrict__ dst, float* __restrict__ agg) {
    long long gid = (long long)blockIdx.x * blockDim.x + threadIdx.x;
    int e = (int)(gid >> 6);
    int f = (int)(gid & 63);
    if (e >= NE || f >= H) return;
    int s = src[e];
    int d = dst[e];
    float v = m[s * H + f];
    atomicAdd(&agg[d * H + f], v);
}

// ---------------- fused GRUCell ----------------
// gi = agg @ W_ih^T + b_ih ; gh = h @ W_hh^T + b_hh
// r=sig(i_r+h_r), z=sig(i_z+h_z), n=tanh(i_n+r*h_n), h' = (1-z)*n + z*h
__global__ void gru(const float* __restrict__ agg, const float* __restrict__ hin,
                    const float* __restrict__ W_ih, const float* __restrict__ W_hh,
                    const float* __restrict__ b_ih, const float* __restrict__ b_hh,
                    float* __restrict__ hout, int n_total) {
    __shared__ float Wi[H3 * H];
    __shared__ float Wh[H3 * H];
    for (int i = threadIdx.x; i < H3 * H; i += blockDim.x) {
        Wi[i] = W_ih[i];
        Wh[i] = W_hh[i];
    }
    __syncthreads();
    int t = blockIdx.x * blockDim.x + threadIdx.x;
    if (t >= n_total) return;
    int n = t / H, f = t % H;
    const float* ar = agg + n * H;
    const float* hr = hin + n * H;
    float ir = 0.f, iz = 0.f, inn = 0.f, hrr = 0.f, hz = 0.f, hn = 0.f;
    const float* wi_r = Wi + f * H;
    const float* wi_z = Wi + (f + H) * H;
    const float* wi_n = Wi + (f + 2 * H) * H;
    const float* wh_r = Wh + f * H;
    const float* wh_z = Wh + (f + H) * H;
    const float* wh_n = Wh + (f + 2 * H) * H;
#pragma unroll
    for (int k = 0; k < H; ++k) {
        float a = ar[k], hh = hr[k];
        ir  += a * wi_r[k];
        iz  += a * wi_z[k];
        inn += a * wi_n[k];
        hrr += hh * wh_r[k];
        hz  += hh * wh_z[k];
        hn  += hh * wh_n[k];
    }
    ir += b_ih[f]; iz += b_ih[f + H]; inn += b_ih[f + 2 * H];
    hrr += b_hh[f]; hz += b_hh[f + H]; hn += b_hh[f + 2 * H];
    float r = 1.f / (1.f + expf(-(ir + hrr)));
    float z = 1.f / (1.f + expf(-(iz + hz)));
    float nv = tanhf(inn + r * hn);
    hout[t] = (1.f - z) * nv + z * hr[f];
}

// ---------------- segment-sum pool via atomics ----------------
__global__ void pool(const float* __restrict__ h, const int* __restrict__ batch,
                     float* __restrict__ g, int n_total) {
    int t = blockIdx.x * blockDim.x + threadIdx.x;
    if (t >= n_total) return;
    int n = t / H, f = t % H;
    atomicAdd(&g[batch[n] * H + f], h[t]);
}

// ---------------- dense layer: out = act(in @ W^T + b) ----------------
// W is [cols, K] row-major; ACT 0 = relu, 1 = sigmoid
template <int K, int ACT>
__global__ void dense(const float* __restrict__ in, const float* __restrict__ W,
                      const float* __restrict__ b, float* __restrict__ out,
                      int rows, int cols) {
    int t = blockIdx.x * blockDim.x + threadIdx.x;
    if (t >= rows * cols) return;
    int r = t / cols, c = t % cols;
    const float* ir = in + r * K;
    const float* wr = W + c * K;
    float acc = b[c];
#pragma unroll 4
    for (int k = 0; k < K; ++k) acc += ir[k] * wr[k];
    out[t] = (ACT == 0) ? fmaxf(acc, 0.f) : 1.f / (1.f + expf(-acc));
}

extern "C" void kernel_launch(void* const* d_in, const int* in_sizes, int n_in,
                              void* d_out, int out_size, void* d_ws, size_t ws_size,
                              hipStream_t stream) {
    const float* x     = (const float*)d_in[0];
    const int*   ei    = (const int*)d_in[1];
    const int*   batch = (const int*)d_in[2];
    const float* W     = (const float*)d_in[3];
    const float* W_ih  = (const float*)d_in[4];
    const float* W_hh  = (const float*)d_in[5];
    const float* b_ih  = (const float*)d_in[6];
    const float* b_hh  = (const float*)d_in[7];
    const float* W1    = (const float*)d_in[8];
    const float* b1    = (const float*)d_in[9];
    const float* W2    = (const float*)d_in[10];
    const float* b2    = (const float*)d_in[11];
    const float* W3    = (const float*)d_in[12];
    const float* b3    = (const float*)d_in[13];
    const float* Wp    = (const float*)d_in[14];
    const float* bp    = (const float*)d_in[15];
    float* out = (float*)d_out;

    const int* src = ei;
    const int* dst = ei + NE;

    char* ws = (char*)d_ws;
    float* m   = (float*)ws;  ws += (size_t)NN * H * sizeof(float);
    float* agg = (float*)ws;  ws += (size_t)NN * H * sizeof(float);
    float* ha  = (float*)ws;  ws += (size_t)NN * H * sizeof(float);
    float* hb  = (float*)ws;  ws += (size_t)NN * H * sizeof(float);
    float* g   = (float*)ws;  ws += (size_t)NG * H * sizeof(float);
    float* f1  = (float*)ws;  ws += (size_t)NG * FFD * sizeof(float);
    float* f2  = (float*)ws;  ws += (size_t)NG * FFD * sizeof(float);
    float* f3  = (float*)ws;  ws += (size_t)NG * FFD * sizeof(float);

    const int nt = NN * H;                 // 4,300,000
    const int blk = 256;
    const int grid_nt = (nt + blk - 1) / blk;
    const long long sc_threads = (long long)NE * 64;
    const int grid_sc = (int)((sc_threads + blk - 1) / blk);

    const float* hin = x;
    float* hout = ha;
    for (int l = 0; l < 5; ++l) {
        mm_hW<<<grid_nt, blk, 0, stream>>>(hin, W + (size_t)l * H * H, m, nt);
        hipMemsetAsync(agg, 0, (size_t)NN * H * sizeof(float), stream);
        scatter_add<<<grid_sc, blk, 0, stream>>>(m, src, dst, agg);
        gru<<<grid_nt, blk, 0, stream>>>(agg, hin, W_ih, W_hh, b_ih, b_hh, hout, nt);
        hin = hout;
        hout = (hout == ha) ? hb : ha;
    }

    hipMemsetAsync(g, 0, (size_t)NG * H * sizeof(float), stream);
    pool<<<grid_nt, blk, 0, stream>>>(hin, batch, g, nt);

    dense<H, 0><<<(NG * FFD + blk - 1) / blk, blk, 0, stream>>>(g,  W1, b1, f1, NG, FFD);
    dense<FFD, 0><<<(NG * FFD + blk - 1) / blk, blk, 0, stream>>>(f1, W2, b2, f2, NG, FFD);
    dense<FFD, 0><<<(NG * FFD + blk - 1) / blk, blk, 0, stream>>>(f2, W3, b3, f3, NG, FFD);
    dense<FFD, 1><<<(NG * NLB + blk - 1) / blk, blk, 0, stream>>>(f3, Wp, bp, out, NG, NLB);
}

// Round 2
// 1737.942 us; speedup vs baseline: 3.0924x; 3.0924x over previous
//
#include <hip/hip_runtime.h>
#include <math.h>

#define H 43
#define H3 129
#define NN 100000
#define NE 1600000
#define NG 2048
#define FFD 392
#define NLB 138
#define SB 256                    // scan block size
#define NBLK ((NN + SB - 1) / SB) // 391
#define RG 8                      // nodes per wave in gru
#define GRU_BLOCKS 768
#define NGRP ((NN + RG - 1) / RG) // 12500

// ---------- CSR build ----------
__global__ void hist(const int* __restrict__ dst, int* __restrict__ deg) {
    int e = blockIdx.x * blockDim.x + threadIdx.x;
    if (e >= NE) return;
    atomicAdd(&deg[dst[e]], 1);
}

__global__ void scan1(const int* __restrict__ deg, int* __restrict__ tmp, int* __restrict__ bsum) {
    __shared__ int s[SB];
    int i = blockIdx.x * SB + threadIdx.x;
    int v = (i < NN) ? deg[i] : 0;
    s[threadIdx.x] = v;
    __syncthreads();
    for (int off = 1; off < SB; off <<= 1) {
        int t = (threadIdx.x >= (unsigned)off) ? s[threadIdx.x - off] : 0;
        __syncthreads();
        s[threadIdx.x] += t;
        __syncthreads();
    }
    if (i < NN) tmp[i] = s[threadIdx.x];
    if (threadIdx.x == SB - 1) bsum[blockIdx.x] = s[SB - 1];
}

__global__ void scan2(const int* __restrict__ bsum, int* __restrict__ boff) {
    __shared__ int s[512];
    int v = (threadIdx.x < NBLK) ? bsum[threadIdx.x] : 0;
    s[threadIdx.x] = v;
    __syncthreads();
    for (int off = 1; off < 512; off <<= 1) {
        int t = (threadIdx.x >= (unsigned)off) ? s[threadIdx.x - off] : 0;
        __syncthreads();
        s[threadIdx.x] += t;
        __syncthreads();
    }
    boff[threadIdx.x] = s[threadIdx.x] - v; // exclusive
}

__global__ void scan3(const int* __restrict__ deg, const int* __restrict__ tmp,
                      const int* __restrict__ boff, int* __restrict__ rowptr) {
    int i = blockIdx.x * blockDim.x + threadIdx.x;
    if (i < NN) rowptr[i] = tmp[i] - deg[i] + boff[i / SB];
    if (i == NN) rowptr[NN] = NE;
}

__global__ void copy_pos(const int* __restrict__ rowptr, int* __restrict__ pos) {
    int i = blockIdx.x * blockDim.x + threadIdx.x;
    if (i < NN) pos[i] = rowptr[i];
}

__global__ void fill(const int* __restrict__ src, const int* __restrict__ dst,
                     int* __restrict__ pos, int* __restrict__ eadj) {
    int e = blockIdx.x * blockDim.x + threadIdx.x;
    if (e >= NE) return;
    int slot = atomicAdd(&pos[dst[e]], 1);
    eadj[slot] = src[e];
}

// ---------- Wc[l] = W[l] @ W_ih^T  -> [5][43][129] ----------
__global__ void wc_build(const float* __restrict__ W, const float* __restrict__ W_ih,
                         float* __restrict__ Wc) {
    int t = blockIdx.x * blockDim.x + threadIdx.x;
    if (t >= 5 * H * H3) return;
    int l = t / (H * H3);
    int rem = t % (H * H3);
    int k = rem / H3, j = rem % H3;
    const float* Wl = W + l * H * H;
    float acc = 0.f;
#pragma unroll
    for (int c = 0; c < H; ++c) acc += Wl[k * H + c] * W_ih[j * H + c];
    Wc[t] = acc;
}

// ---------- aggH[n] = sum over incoming edges of h[src] ----------
__global__ void gather(const float* __restrict__ h, const int* __restrict__ rowptr,
                       const int* __restrict__ eadj, float* __restrict__ aggH) {
    int wid = (blockIdx.x * blockDim.x + threadIdx.x) >> 6;
    int lane = threadIdx.x & 63;
    if (wid >= NN) return;
    int beg = rowptr[wid], end = rowptr[wid + 1];
    float acc = 0.f;
    for (int e = beg; e < end; ++e) {
        int s = eadj[e];
        if (lane < H) acc += h[s * H + lane];
    }
    if (lane < H) aggH[wid * H + lane] = acc;
}

// ---------- fused GRU:  gi = aggH@Wc + b_ih ; gh = h@W_hh^T + b_hh ----------
__global__ __launch_bounds__(256) void gru_f(const float* __restrict__ aggH,
                                             const float* __restrict__ hin,
                                             const float* __restrict__ Wc_l,
                                             const float* __restrict__ W_hh,
                                             const float* __restrict__ b_ih,
                                             const float* __restrict__ b_hh,
                                             float* __restrict__ hout) {
    __shared__ float Wcs[H * H3]; // [k][j] 43x129
    __shared__ float Whs[H3 * H]; // [j][k] 129x43
    __shared__ float bi[H3], bh[H3];
    for (int i = threadIdx.x; i < H * H3; i += 256) {
        Wcs[i] = Wc_l[i];
        Whs[i] = W_hh[i];
    }
    for (int i = threadIdx.x; i < H3; i += 256) {
        bi[i] = b_ih[i];
        bh[i] = b_hh[i];
    }
    __syncthreads();

    int lane = threadIdx.x & 63;
    int f = lane;
    int fc = (f < H) ? f : 0; // safe index for idle lanes
    int wid = (blockIdx.x * blockDim.x + threadIdx.x) >> 6;
    const int nwaves = GRU_BLOCKS * 4;

    for (int grp = wid; grp < NGRP; grp += nwaves) {
        int n0 = grp * RG;
        float ir[RG], iz[RG], in_[RG], hr_[RG], hz[RG], hn[RG];
#pragma unroll
        for (int r = 0; r < RG; ++r) { ir[r] = iz[r] = in_[r] = hr_[r] = hz[r] = hn[r] = 0.f; }

        for (int k = 0; k < H; ++k) {
            float wcr = Wcs[k * H3 + fc];
            float wcz = Wcs[k * H3 + fc + H];
            float wcn = Wcs[k * H3 + fc + 2 * H];
            float whr = Whs[fc * H + k];
            float whz = Whs[(fc + H) * H + k];
            float whn = Whs[(fc + 2 * H) * H + k];
#pragma unroll
            for (int r = 0; r < RG; ++r) {
                float a = aggH[(n0 + r) * H + k];
                float hh = hin[(n0 + r) * H + k];
                ir[r] += a * wcr;
                iz[r] += a * wcz;
                in_[r] += a * wcn;
                hr_[r] += hh * whr;
                hz[r] += hh * whz;
                hn[r] += hh * whn;
            }
        }
#pragma unroll
        for (int r = 0; r < RG; ++r) {
            float gr = ir[r] + bi[fc] + hr_[r] + bh[fc];
            float gz = iz[r] + bi[fc + H] + hz[r] + bh[fc + H];
            float rr = 1.f / (1.f + expf(-gr));
            float zz = 1.f / (1.f + expf(-gz));
            float nn = tanhf(in_[r] + bi[fc + 2 * H] + rr * (hn[r] + bh[fc + 2 * H]));
            if (f < H) {
                float hprev = hin[(n0 + r) * H + f];
                hout[(n0 + r) * H + f] = (1.f - zz) * nn + zz * hprev;
            }
        }
    }
}

// ---------- pool: batch is sorted -> binary search graph ranges ----------
__global__ void pool_seg(const float* __restrict__ h, const int* __restrict__ batch,
                         float* __restrict__ g) {
    int wid = (blockIdx.x * blockDim.x + threadIdx.x) >> 6;
    int lane = threadIdx.x & 63;
    if (wid >= NG) return;
    // lower_bound for wid and wid+1
    int lo = 0, hi = NN;
    while (lo < hi) { int mid = (lo + hi) >> 1; if (batch[mid] < wid) lo = mid + 1; else hi = mid; }
    int beg = lo;
    lo = beg; hi = NN;
    while (lo < hi) { int mid = (lo + hi) >> 1; if (batch[mid] < wid + 1) lo = mid + 1; else hi = mid; }
    int end = lo;
    float acc = 0.f;
    if (lane < H) {
        for (int n = beg; n < end; ++n) acc += h[n * H + lane];
        g[wid * H + lane] = acc;
    }
}

// ---------- dense: out = act(in @ W^T + b), RB-row register blocking ----------
template <int K, int ACT, int RB>
__global__ void dense_rb(const float* __restrict__ in, const float* __restrict__ W,
                         const float* __restrict__ b, float* __restrict__ out,
                         int rows, int cols) {
    int t = blockIdx.x * blockDim.x + threadIdx.x;
    int ngroups = rows / RB;
    if (t >= ngroups * cols) return;
    int c = t % cols;
    int r0 = (t / cols) * RB;
    float acc[RB];
#pragma unroll
    for (int r = 0; r < RB; ++r) acc[r] = b[c];
    const float* wr = W + (size_t)c * K;
    for (int k = 0; k < K; ++k) {
        float w = wr[k];
#pragma unroll
        for (int r = 0; r < RB; ++r) acc[r] += in[(r0 + r) * K + k] * w;
    }
#pragma unroll
    for (int r = 0; r < RB; ++r) {
        float v = acc[r];
        v = (ACT == 0) ? fmaxf(v, 0.f) : 1.f / (1.f + expf(-v));
        out[(r0 + r) * cols + c] = v;
    }
}

static inline size_t rnd256(size_t x) { return (x + 255) & ~(size_t)255; }

extern "C" void kernel_launch(void* const* d_in, const int* in_sizes, int n_in,
                              void* d_out, int out_size, void* d_ws, size_t ws_size,
                              hipStream_t stream) {
    const float* x     = (const float*)d_in[0];
    const int*   ei    = (const int*)d_in[1];
    const int*   batch = (const int*)d_in[2];
    const float* W     = (const float*)d_in[3];
    const float* W_ih  = (const float*)d_in[4];
    const float* W_hh  = (const float*)d_in[5];
    const float* b_ih  = (const float*)d_in[6];
    const float* b_hh  = (const float*)d_in[7];
    const float* W1    = (const float*)d_in[8];
    const float* b1    = (const float*)d_in[9];
    const float* W2    = (const float*)d_in[10];
    const float* b2    = (const float*)d_in[11];
    const float* W3    = (const float*)d_in[12];
    const float* b3    = (const float*)d_in[13];
    const float* Wp    = (const float*)d_in[14];
    const float* bp    = (const float*)d_in[15];
    float* out = (float*)d_out;

    const int* src = ei;
    const int* dst = ei + NE;

    char* ws = (char*)d_ws;
    float* aggH  = (float*)ws; ws += rnd256((size_t)NN * H * sizeof(float));
    float* ha    = (float*)ws; ws += rnd256((size_t)NN * H * sizeof(float));
    float* hb    = (float*)ws; ws += rnd256((size_t)NN * H * sizeof(float));
    int*   eadj  = (int*)ws;   ws += rnd256((size_t)NE * sizeof(int));
    int*   deg   = (int*)ws;   ws += rnd256((size_t)NN * sizeof(int));
    int*   tmp   = (int*)ws;   ws += rnd256((size_t)NN * sizeof(int));
    int*   rowp  = (int*)ws;   ws += rnd256((size_t)(NN + 1) * sizeof(int));
    int*   pos   = (int*)ws;   ws += rnd256((size_t)NN * sizeof(int));
    int*   bsum  = (int*)ws;   ws += rnd256((size_t)512 * sizeof(int));
    int*   boff  = (int*)ws;   ws += rnd256((size_t)512 * sizeof(int));
    float* Wc    = (float*)ws; ws += rnd256((size_t)5 * H * H3 * sizeof(float));
    float* g     = (float*)ws; ws += rnd256((size_t)NG * H * sizeof(float));
    float* f1    = (float*)ws; ws += rnd256((size_t)NG * FFD * sizeof(float));
    float* f2    = (float*)ws; ws += rnd256((size_t)NG * FFD * sizeof(float));
    float* f3    = (float*)ws; ws += rnd256((size_t)NG * FFD * sizeof(float));

    const int blk = 256;
    const int grid_e = (NE + blk - 1) / blk;

    // ---- CSR build (once; reused by all 5 layers) ----
    hipMemsetAsync(deg, 0, (size_t)NN * sizeof(int), stream);
    hist<<<grid_e, blk, 0, stream>>>(dst, deg);
    scan1<<<NBLK, SB, 0, stream>>>(deg, tmp, bsum);
    scan2<<<1, 512, 0, stream>>>(bsum, boff);
    scan3<<<(NN + 1 + blk - 1) / blk, blk, 0, stream>>>(deg, tmp, boff, rowp);
    copy_pos<<<(NN + blk - 1) / blk, blk, 0, stream>>>(rowp, pos);
    fill<<<grid_e, blk, 0, stream>>>(src, dst, pos, eadj);

    // ---- fold W[l] into GRU input weights ----
    wc_build<<<(5 * H * H3 + blk - 1) / blk, blk, 0, stream>>>(W, W_ih, Wc);

    // ---- 5 GGC layers ----
    const int grid_gather = (NN * 64 + blk - 1) / blk; // one wave per node
    const float* hin = x;
    float* hout = ha;
    for (int l = 0; l < 5; ++l) {
        gather<<<grid_gather, blk, 0, stream>>>(hin, rowp, eadj, aggH);
        gru_f<<<GRU_BLOCKS, blk, 0, stream>>>(aggH, hin, Wc + (size_t)l * H * H3,
                                              W_hh, b_ih, b_hh, hout);
        hin = hout;
        hout = (hout == ha) ? hb : ha;
    }

    // ---- pool (batch sorted -> binary search ranges) ----
    pool_seg<<<(NG * 64 + blk - 1) / blk, blk, 0, stream>>>(hin, batch, g);

    // ---- MLP head ----
    dense_rb<H, 0, 4><<<((NG / 4) * FFD + blk - 1) / blk, blk, 0, stream>>>(g,  W1, b1, f1, NG, FFD);
    dense_rb<FFD, 0, 4><<<((NG / 4) * FFD + blk - 1) / blk, blk, 0, stream>>>(f1, W2, b2, f2, NG, FFD);
    dense_rb<FFD, 0, 4><<<((NG / 4) * FFD + blk - 1) / blk, blk, 0, stream>>>(f2, W3, b3, f3, NG, FFD);
    dense_rb<FFD, 1, 4><<<((NG / 4) * NLB + blk - 1) / blk, blk, 0, stream>>>(f3, Wp, bp, out, NG, NLB);
}

// Round 3
// 1268.028 us; speedup vs baseline: 4.2384x; 1.3706x over previous
//
#include <hip/hip_runtime.h>
#include <math.h>

#define H 43
#define H3 129
#define NN 100000
#define NE 1600000
#define NG 2048
#define FFD 392
#define NLB 138
#define SB 256                    // scan block size
#define NBLK ((NN + SB - 1) / SB) // 391
#define RG 8                      // nodes per wave in gru
#define GRU_BLOCKS 768
#define NGRP ((NN + RG - 1) / RG) // 12500

// ---------- CSR build ----------
__global__ void hist(const int* __restrict__ dst, int* __restrict__ deg) {
    int e = blockIdx.x * blockDim.x + threadIdx.x;
    if (e >= NE) return;
    atomicAdd(&deg[dst[e]], 1);
}

__global__ void scan1(const int* __restrict__ deg, int* __restrict__ tmp, int* __restrict__ bsum) {
    __shared__ int s[SB];
    int i = blockIdx.x * SB + threadIdx.x;
    int v = (i < NN) ? deg[i] : 0;
    s[threadIdx.x] = v;
    __syncthreads();
    for (int off = 1; off < SB; off <<= 1) {
        int t = (threadIdx.x >= (unsigned)off) ? s[threadIdx.x - off] : 0;
        __syncthreads();
        s[threadIdx.x] += t;
        __syncthreads();
    }
    if (i < NN) tmp[i] = s[threadIdx.x];
    if (threadIdx.x == SB - 1) bsum[blockIdx.x] = s[SB - 1];
}

__global__ void scan2(const int* __restrict__ bsum, int* __restrict__ boff) {
    __shared__ int s[512];
    int v = (threadIdx.x < NBLK) ? bsum[threadIdx.x] : 0;
    s[threadIdx.x] = v;
    __syncthreads();
    for (int off = 1; off < 512; off <<= 1) {
        int t = (threadIdx.x >= (unsigned)off) ? s[threadIdx.x - off] : 0;
        __syncthreads();
        s[threadIdx.x] += t;
        __syncthreads();
    }
    boff[threadIdx.x] = s[threadIdx.x] - v; // exclusive
}

__global__ void scan3(const int* __restrict__ deg, const int* __restrict__ tmp,
                      const int* __restrict__ boff, int* __restrict__ rowptr) {
    int i = blockIdx.x * blockDim.x + threadIdx.x;
    if (i < NN) rowptr[i] = tmp[i] - deg[i] + boff[i / SB];
    if (i == NN) rowptr[NN] = NE;
}

__global__ void copy_pos(const int* __restrict__ rowptr, int* __restrict__ pos) {
    int i = blockIdx.x * blockDim.x + threadIdx.x;
    if (i < NN) pos[i] = rowptr[i];
}

__global__ void fill(const int* __restrict__ src, const int* __restrict__ dst,
                     int* __restrict__ pos, int* __restrict__ eadj) {
    int e = blockIdx.x * blockDim.x + threadIdx.x;
    if (e >= NE) return;
    int slot = atomicAdd(&pos[dst[e]], 1);
    eadj[slot] = src[e];
}

// ---------- Wc[l] = W[l] @ W_ih^T  -> [5][43][129] ----------
__global__ void wc_build(const float* __restrict__ W, const float* __restrict__ W_ih,
                         float* __restrict__ Wc) {
    int t = blockIdx.x * blockDim.x + threadIdx.x;
    if (t >= 5 * H * H3) return;
    int l = t / (H * H3);
    int rem = t % (H * H3);
    int k = rem / H3, j = rem % H3;
    const float* Wl = W + l * H * H;
    float acc = 0.f;
#pragma unroll
    for (int c = 0; c < H; ++c) acc += Wl[k * H + c] * W_ih[j * H + c];
    Wc[t] = acc;
}

// ---------- aggH[n] = sum over incoming edges of h[src] ----------
// One node per wave. Coalesced index load, shfl-broadcast, 8 independent
// row-loads in flight to break the eadj->h dependent-latency chain.
__global__ __launch_bounds__(256) void gather(const float* __restrict__ h,
                                              const int* __restrict__ rowptr,
                                              const int* __restrict__ eadj,
                                              float* __restrict__ aggH) {
    int wid = (blockIdx.x * blockDim.x + threadIdx.x) >> 6;
    int lane = threadIdx.x & 63;
    if (wid >= NN) return;
    int beg = rowptr[wid], end = rowptr[wid + 1];
    int fc = (lane < H) ? lane : 0;
    float acc = 0.f;
    for (int base = beg; base < end; base += 64) {
        int cnt = min(64, end - base);
        int idx = (base + lane < end) ? eadj[base + lane] : 0;
        int r = 0;
        for (; r + 8 <= cnt; r += 8) {
            int s0 = __shfl(idx, r + 0), s1 = __shfl(idx, r + 1);
            int s2 = __shfl(idx, r + 2), s3 = __shfl(idx, r + 3);
            int s4 = __shfl(idx, r + 4), s5 = __shfl(idx, r + 5);
            int s6 = __shfl(idx, r + 6), s7 = __shfl(idx, r + 7);
            float v0 = h[(size_t)s0 * H + fc];
            float v1 = h[(size_t)s1 * H + fc];
            float v2 = h[(size_t)s2 * H + fc];
            float v3 = h[(size_t)s3 * H + fc];
            float v4 = h[(size_t)s4 * H + fc];
            float v5 = h[(size_t)s5 * H + fc];
            float v6 = h[(size_t)s6 * H + fc];
            float v7 = h[(size_t)s7 * H + fc];
            acc += ((v0 + v1) + (v2 + v3)) + ((v4 + v5) + (v6 + v7));
        }
        if (r + 4 <= cnt) {
            int s0 = __shfl(idx, r + 0), s1 = __shfl(idx, r + 1);
            int s2 = __shfl(idx, r + 2), s3 = __shfl(idx, r + 3);
            float v0 = h[(size_t)s0 * H + fc];
            float v1 = h[(size_t)s1 * H + fc];
            float v2 = h[(size_t)s2 * H + fc];
            float v3 = h[(size_t)s3 * H + fc];
            acc += (v0 + v1) + (v2 + v3);
            r += 4;
        }
        for (; r < cnt; ++r) {
            int s = __shfl(idx, r);
            acc += h[(size_t)s * H + fc];
        }
    }
    if (lane < H) aggH[wid * H + lane] = acc;
}

// ---------- fused GRU:  gi = aggH@Wc + b_ih ; gh = h@W_hh^T + b_hh ----------
__global__ __launch_bounds__(256) void gru_f(const float* __restrict__ aggH,
                                             const float* __restrict__ hin,
                                             const float* __restrict__ Wc_l,
                                             const float* __restrict__ W_hh,
                                             const float* __restrict__ b_ih,
                                             const float* __restrict__ b_hh,
                                             float* __restrict__ hout) {
    __shared__ float Wcs[H * H3]; // [k][j] 43x129
    __shared__ float Whs[H3 * H]; // [j][k] 129x43
    __shared__ float bi[H3], bh[H3];
    for (int i = threadIdx.x; i < H * H3; i += 256) {
        Wcs[i] = Wc_l[i];
        Whs[i] = W_hh[i];
    }
    for (int i = threadIdx.x; i < H3; i += 256) {
        bi[i] = b_ih[i];
        bh[i] = b_hh[i];
    }
    __syncthreads();

    int lane = threadIdx.x & 63;
    int f = lane;
    int fc = (f < H) ? f : 0; // safe index for idle lanes
    int wid = (blockIdx.x * blockDim.x + threadIdx.x) >> 6;
    const int nwaves = GRU_BLOCKS * 4;

    for (int grp = wid; grp < NGRP; grp += nwaves) {
        int n0 = grp * RG;
        float ir[RG], iz[RG], in_[RG], hr_[RG], hz[RG], hn[RG];
#pragma unroll
        for (int r = 0; r < RG; ++r) { ir[r] = iz[r] = in_[r] = hr_[r] = hz[r] = hn[r] = 0.f; }

        for (int k = 0; k < H; ++k) {
            float wcr = Wcs[k * H3 + fc];
            float wcz = Wcs[k * H3 + fc + H];
            float wcn = Wcs[k * H3 + fc + 2 * H];
            float whr = Whs[fc * H + k];
            float whz = Whs[(fc + H) * H + k];
            float whn = Whs[(fc + 2 * H) * H + k];
#pragma unroll
            for (int r = 0; r < RG; ++r) {
                float a = aggH[(n0 + r) * H + k];
                float hh = hin[(n0 + r) * H + k];
                ir[r] += a * wcr;
                iz[r] += a * wcz;
                in_[r] += a * wcn;
                hr_[r] += hh * whr;
                hz[r] += hh * whz;
                hn[r] += hh * whn;
            }
        }
#pragma unroll
        for (int r = 0; r < RG; ++r) {
            float gr = ir[r] + bi[fc] + hr_[r] + bh[fc];
            float gz = iz[r] + bi[fc + H] + hz[r] + bh[fc + H];
            float rr = 1.f / (1.f + expf(-gr));
            float zz = 1.f / (1.f + expf(-gz));
            float nn = tanhf(in_[r] + bi[fc + 2 * H] + rr * (hn[r] + bh[fc + 2 * H]));
            if (f < H) {
                float hprev = hin[(n0 + r) * H + f];
                hout[(n0 + r) * H + f] = (1.f - zz) * nn + zz * hprev;
            }
        }
    }
}

// ---------- pool: batch is sorted -> binary search graph ranges ----------
__global__ void pool_seg(const float* __restrict__ h, const int* __restrict__ batch,
                         float* __restrict__ g) {
    int wid = (blockIdx.x * blockDim.x + threadIdx.x) >> 6;
    int lane = threadIdx.x & 63;
    if (wid >= NG) return;
    int lo = 0, hi = NN;
    while (lo < hi) { int mid = (lo + hi) >> 1; if (batch[mid] < wid) lo = mid + 1; else hi = mid; }
    int beg = lo;
    lo = beg; hi = NN;
    while (lo < hi) { int mid = (lo + hi) >> 1; if (batch[mid] < wid + 1) lo = mid + 1; else hi = mid; }
    int end = lo;
    float acc = 0.f;
    if (lane < H) {
        for (int n = beg; n < end; ++n) acc += h[n * H + lane];
        g[wid * H + lane] = acc;
    }
}

// ---------- dense: out = act(in @ W^T + b), RB-row register blocking ----------
template <int K, int ACT, int RB>
__global__ void dense_rb(const float* __restrict__ in, const float* __restrict__ W,
                         const float* __restrict__ b, float* __restrict__ out,
                         int rows, int cols) {
    int t = blockIdx.x * blockDim.x + threadIdx.x;
    int ngroups = rows / RB;
    if (t >= ngroups * cols) return;
    int c = t % cols;
    int r0 = (t / cols) * RB;
    float acc[RB];
#pragma unroll
    for (int r = 0; r < RB; ++r) acc[r] = b[c];
    const float* wr = W + (size_t)c * K;
    for (int k = 0; k < K; ++k) {
        float w = wr[k];
#pragma unroll
        for (int r = 0; r < RB; ++r) acc[r] += in[(r0 + r) * K + k] * w;
    }
#pragma unroll
    for (int r = 0; r < RB; ++r) {
        float v = acc[r];
        v = (ACT == 0) ? fmaxf(v, 0.f) : 1.f / (1.f + expf(-v));
        out[(r0 + r) * cols + c] = v;
    }
}

static inline size_t rnd256(size_t x) { return (x + 255) & ~(size_t)255; }

extern "C" void kernel_launch(void* const* d_in, const int* in_sizes, int n_in,
                              void* d_out, int out_size, void* d_ws, size_t ws_size,
                              hipStream_t stream) {
    const float* x     = (const float*)d_in[0];
    const int*   ei    = (const int*)d_in[1];
    const int*   batch = (const int*)d_in[2];
    const float* W     = (const float*)d_in[3];
    const float* W_ih  = (const float*)d_in[4];
    const float* W_hh  = (const float*)d_in[5];
    const float* b_ih  = (const float*)d_in[6];
    const float* b_hh  = (const float*)d_in[7];
    const float* W1    = (const float*)d_in[8];
    const float* b1    = (const float*)d_in[9];
    const float* W2    = (const float*)d_in[10];
    const float* b2    = (const float*)d_in[11];
    const float* W3    = (const float*)d_in[12];
    const float* b3    = (const float*)d_in[13];
    const float* Wp    = (const float*)d_in[14];
    const float* bp    = (const float*)d_in[15];
    float* out = (float*)d_out;

    const int* src = ei;
    const int* dst = ei + NE;

    char* ws = (char*)d_ws;
    float* aggH  = (float*)ws; ws += rnd256((size_t)NN * H * sizeof(float));
    float* ha    = (float*)ws; ws += rnd256((size_t)NN * H * sizeof(float));
    float* hb    = (float*)ws; ws += rnd256((size_t)NN * H * sizeof(float));
    int*   eadj  = (int*)ws;   ws += rnd256((size_t)NE * sizeof(int));
    int*   deg   = (int*)ws;   ws += rnd256((size_t)NN * sizeof(int));
    int*   tmp   = (int*)ws;   ws += rnd256((size_t)NN * sizeof(int));
    int*   rowp  = (int*)ws;   ws += rnd256((size_t)(NN + 1) * sizeof(int));
    int*   pos   = (int*)ws;   ws += rnd256((size_t)NN * sizeof(int));
    int*   bsum  = (int*)ws;   ws += rnd256((size_t)512 * sizeof(int));
    int*   boff  = (int*)ws;   ws += rnd256((size_t)512 * sizeof(int));
    float* Wc    = (float*)ws; ws += rnd256((size_t)5 * H * H3 * sizeof(float));
    float* g     = (float*)ws; ws += rnd256((size_t)NG * H * sizeof(float));
    float* f1    = (float*)ws; ws += rnd256((size_t)NG * FFD * sizeof(float));
    float* f2    = (float*)ws; ws += rnd256((size_t)NG * FFD * sizeof(float));
    float* f3    = (float*)ws; ws += rnd256((size_t)NG * FFD * sizeof(float));

    const int blk = 256;
    const int grid_e = (NE + blk - 1) / blk;

    // ---- CSR build (once; reused by all 5 layers) ----
    hipMemsetAsync(deg, 0, (size_t)NN * sizeof(int), stream);
    hist<<<grid_e, blk, 0, stream>>>(dst, deg);
    scan1<<<NBLK, SB, 0, stream>>>(deg, tmp, bsum);
    scan2<<<1, 512, 0, stream>>>(bsum, boff);
    scan3<<<(NN + 1 + blk - 1) / blk, blk, 0, stream>>>(deg, tmp, boff, rowp);
    copy_pos<<<(NN + blk - 1) / blk, blk, 0, stream>>>(rowp, pos);
    fill<<<grid_e, blk, 0, stream>>>(src, dst, pos, eadj);

    // ---- fold W[l] into GRU input weights ----
    wc_build<<<(5 * H * H3 + blk - 1) / blk, blk, 0, stream>>>(W, W_ih, Wc);

    // ---- 5 GGC layers ----
    const int grid_gather = (NN * 64 + blk - 1) / blk; // one wave per node
    const float* hin = x;
    float* hout = ha;
    for (int l = 0; l < 5; ++l) {
        gather<<<grid_gather, blk, 0, stream>>>(hin, rowp, eadj, aggH);
        gru_f<<<GRU_BLOCKS, blk, 0, stream>>>(aggH, hin, Wc + (size_t)l * H * H3,
                                              W_hh, b_ih, b_hh, hout);
        hin = hout;
        hout = (hout == ha) ? hb : ha;
    }

    // ---- pool (batch sorted -> binary search ranges) ----
    pool_seg<<<(NG * 64 + blk - 1) / blk, blk, 0, stream>>>(hin, batch, g);

    // ---- MLP head ----
    dense_rb<H, 0, 4><<<((NG / 4) * FFD + blk - 1) / blk, blk, 0, stream>>>(g,  W1, b1, f1, NG, FFD);
    dense_rb<FFD, 0, 4><<<((NG / 4) * FFD + blk - 1) / blk, blk, 0, stream>>>(f1, W2, b2, f2, NG, FFD);
    dense_rb<FFD, 0, 4><<<((NG / 4) * FFD + blk - 1) / blk, blk, 0, stream>>>(f2, W3, b3, f3, NG, FFD);
    dense_rb<FFD, 1, 4><<<((NG / 4) * NLB + blk - 1) / blk, blk, 0, stream>>>(f3, Wp, bp, out, NG, NLB);
}

// Round 4
// 1154.844 us; speedup vs baseline: 4.6538x; 1.0980x over previous
//
#include <hip/hip_runtime.h>
#include <math.h>

#define H 43
#define H3 129
#define HP 64                     // padded row (fp16) -> 128B, line-aligned
#define NN 100000
#define NE 1600000
#define NG 2048
#define FFD 392
#define NLB 138
#define SB 256                    // scan block size
#define NBLK ((NN + SB - 1) / SB) // 391
#define RG 8                      // nodes per wave in gru
#define GRU_BLOCKS 768
#define NGRP ((NN + RG - 1) / RG) // 12500
#define NXCD 8
#define RANGE (NN / NXCD)         // 12500 dst-nodes per XCD shard
#define FBLK 2048                 // fill/hist grid: 256 blocks per shard
#define CHUNK ((NE + 255) / 256)  // 6250 edges per block-chunk

// ---------- CSR build (XCD-sharded: group g = blockIdx&7 owns dst range g) ----------
__global__ void hist_sh(const int* __restrict__ dst, int* __restrict__ deg) {
    int g = blockIdx.x & (NXCD - 1);
    int i = blockIdx.x >> 3;
    int lo = g * RANGE, hi = lo + RANGE;
    int e0 = i * CHUNK;
    int e1 = min(NE, e0 + CHUNK);
    for (int e = e0 + threadIdx.x; e < e1; e += blockDim.x) {
        int d = dst[e];
        if (d >= lo && d < hi) atomicAdd(&deg[d], 1);
    }
}

__global__ void fill_sh(const int* __restrict__ src, const int* __restrict__ dst,
                        int* __restrict__ pos, int* __restrict__ eadj) {
    int g = blockIdx.x & (NXCD - 1);
    int i = blockIdx.x >> 3;
    int lo = g * RANGE, hi = lo + RANGE;
    int e0 = i * CHUNK;
    int e1 = min(NE, e0 + CHUNK);
    for (int e = e0 + threadIdx.x; e < e1; e += blockDim.x) {
        int d = dst[e];
        if (d >= lo && d < hi) {
            int slot = atomicAdd(&pos[d], 1);
            eadj[slot] = src[e];
        }
    }
}

__global__ void scan1(const int* __restrict__ deg, int* __restrict__ tmp, int* __restrict__ bsum) {
    __shared__ int s[SB];
    int i = blockIdx.x * SB + threadIdx.x;
    int v = (i < NN) ? deg[i] : 0;
    s[threadIdx.x] = v;
    __syncthreads();
    for (int off = 1; off < SB; off <<= 1) {
        int t = (threadIdx.x >= (unsigned)off) ? s[threadIdx.x - off] : 0;
        __syncthreads();
        s[threadIdx.x] += t;
        __syncthreads();
    }
    if (i < NN) tmp[i] = s[threadIdx.x];
    if (threadIdx.x == SB - 1) bsum[blockIdx.x] = s[SB - 1];
}

__global__ void scan2(const int* __restrict__ bsum, int* __restrict__ boff) {
    __shared__ int s[512];
    int v = (threadIdx.x < NBLK) ? bsum[threadIdx.x] : 0;
    s[threadIdx.x] = v;
    __syncthreads();
    for (int off = 1; off < 512; off <<= 1) {
        int t = (threadIdx.x >= (unsigned)off) ? s[threadIdx.x - off] : 0;
        __syncthreads();
        s[threadIdx.x] += t;
        __syncthreads();
    }
    boff[threadIdx.x] = s[threadIdx.x] - v; // exclusive
}

__global__ void scan3(const int* __restrict__ deg, const int* __restrict__ tmp,
                      const int* __restrict__ boff, int* __restrict__ rowptr) {
    int i = blockIdx.x * blockDim.x + threadIdx.x;
    if (i < NN) rowptr[i] = tmp[i] - deg[i] + boff[i / SB];
    if (i == NN) rowptr[NN] = NE;
}

__global__ void copy_pos(const int* __restrict__ rowptr, int* __restrict__ pos) {
    int i = blockIdx.x * blockDim.x + threadIdx.x;
    if (i < NN) pos[i] = rowptr[i];
}

// ---------- Wc[l] = W[l] @ W_ih^T  -> [5][43][129] ----------
__global__ void wc_build(const float* __restrict__ W, const float* __restrict__ W_ih,
                         float* __restrict__ Wc) {
    int t = blockIdx.x * blockDim.x + threadIdx.x;
    if (t >= 5 * H * H3) return;
    int l = t / (H * H3);
    int rem = t % (H * H3);
    int k = rem / H3, j = rem % H3;
    const float* Wl = W + l * H * H;
    float acc = 0.f;
#pragma unroll
    for (int c = 0; c < H; ++c) acc += Wl[k * H + c] * W_ih[j * H + c];
    Wc[t] = acc;
}

// ---------- seed fp16 gather table from x ----------
__global__ void conv_x(const float* __restrict__ x, _Float16* __restrict__ hh) {
    int t = blockIdx.x * blockDim.x + threadIdx.x;
    if (t >= NN * HP) return;
    int n = t >> 6, f = t & (HP - 1);
    hh[t] = (f < H) ? (_Float16)x[n * H + f] : (_Float16)0.f;
}

// ---------- aggH[n] = sum over incoming edges of hh[src] (fp16 rows, f32 acc) ----------
__global__ __launch_bounds__(256) void gather(const _Float16* __restrict__ hh,
                                              const int* __restrict__ rowptr,
                                              const int* __restrict__ eadj,
                                              float* __restrict__ aggH) {
    int wid = (blockIdx.x * blockDim.x + threadIdx.x) >> 6;
    int lane = threadIdx.x & 63;
    if (wid >= NN) return;
    int beg = rowptr[wid], end = rowptr[wid + 1];
    int fc = (lane < H) ? lane : 0;
    float acc = 0.f;
    for (int base = beg; base < end; base += 64) {
        int cnt = min(64, end - base);
        int idx = (base + lane < end) ? eadj[base + lane] : 0;
        int r = 0;
        for (; r + 8 <= cnt; r += 8) {
            int s0 = __shfl(idx, r + 0), s1 = __shfl(idx, r + 1);
            int s2 = __shfl(idx, r + 2), s3 = __shfl(idx, r + 3);
            int s4 = __shfl(idx, r + 4), s5 = __shfl(idx, r + 5);
            int s6 = __shfl(idx, r + 6), s7 = __shfl(idx, r + 7);
            float v0 = (float)hh[(size_t)s0 * HP + fc];
            float v1 = (float)hh[(size_t)s1 * HP + fc];
            float v2 = (float)hh[(size_t)s2 * HP + fc];
            float v3 = (float)hh[(size_t)s3 * HP + fc];
            float v4 = (float)hh[(size_t)s4 * HP + fc];
            float v5 = (float)hh[(size_t)s5 * HP + fc];
            float v6 = (float)hh[(size_t)s6 * HP + fc];
            float v7 = (float)hh[(size_t)s7 * HP + fc];
            acc += ((v0 + v1) + (v2 + v3)) + ((v4 + v5) + (v6 + v7));
        }
        if (r + 4 <= cnt) {
            int s0 = __shfl(idx, r + 0), s1 = __shfl(idx, r + 1);
            int s2 = __shfl(idx, r + 2), s3 = __shfl(idx, r + 3);
            float v0 = (float)hh[(size_t)s0 * HP + fc];
            float v1 = (float)hh[(size_t)s1 * HP + fc];
            float v2 = (float)hh[(size_t)s2 * HP + fc];
            float v3 = (float)hh[(size_t)s3 * HP + fc];
            acc += (v0 + v1) + (v2 + v3);
            r += 4;
        }
        for (; r < cnt; ++r) {
            int s = __shfl(idx, r);
            acc += (float)hh[(size_t)s * HP + fc];
        }
    }
    if (lane < H) aggH[wid * H + lane] = acc;
}

// ---------- fused GRU:  gi = aggH@Wc + b_ih ; gh = h@W_hh^T + b_hh ----------
// Also writes the fp16 gather table for the next layer.
__global__ __launch_bounds__(256) void gru_f(const float* __restrict__ aggH,
                                             const float* __restrict__ hin,
                                             const float* __restrict__ Wc_l,
                                             const float* __restrict__ W_hh,
                                             const float* __restrict__ b_ih,
                                             const float* __restrict__ b_hh,
                                             float* __restrict__ hout,
                                             _Float16* __restrict__ hh) {
    __shared__ float Wcs[H * H3]; // [k][j] 43x129
    __shared__ float Whs[H3 * H]; // [j][k] 129x43
    __shared__ float bi[H3], bh[H3];
    for (int i = threadIdx.x; i < H * H3; i += 256) {
        Wcs[i] = Wc_l[i];
        Whs[i] = W_hh[i];
    }
    for (int i = threadIdx.x; i < H3; i += 256) {
        bi[i] = b_ih[i];
        bh[i] = b_hh[i];
    }
    __syncthreads();

    int lane = threadIdx.x & 63;
    int f = lane;
    int fc = (f < H) ? f : 0; // safe index for idle lanes
    int wid = (blockIdx.x * blockDim.x + threadIdx.x) >> 6;
    const int nwaves = GRU_BLOCKS * 4;

    for (int grp = wid; grp < NGRP; grp += nwaves) {
        int n0 = grp * RG;
        float ir[RG], iz[RG], in_[RG], hr_[RG], hz[RG], hn[RG];
#pragma unroll
        for (int r = 0; r < RG; ++r) { ir[r] = iz[r] = in_[r] = hr_[r] = hz[r] = hn[r] = 0.f; }

        for (int k = 0; k < H; ++k) {
            float wcr = Wcs[k * H3 + fc];
            float wcz = Wcs[k * H3 + fc + H];
            float wcn = Wcs[k * H3 + fc + 2 * H];
            float whr = Whs[fc * H + k];
            float whz = Whs[(fc + H) * H + k];
            float whn = Whs[(fc + 2 * H) * H + k];
#pragma unroll
            for (int r = 0; r < RG; ++r) {
                float a = aggH[(n0 + r) * H + k];
                float hh2 = hin[(n0 + r) * H + k];
                ir[r] += a * wcr;
                iz[r] += a * wcz;
                in_[r] += a * wcn;
                hr_[r] += hh2 * whr;
                hz[r] += hh2 * whz;
                hn[r] += hh2 * whn;
            }
        }
#pragma unroll
        for (int r = 0; r < RG; ++r) {
            float gr = ir[r] + bi[fc] + hr_[r] + bh[fc];
            float gz = iz[r] + bi[fc + H] + hz[r] + bh[fc + H];
            float rr = 1.f / (1.f + expf(-gr));
            float zz = 1.f / (1.f + expf(-gz));
            float nn = tanhf(in_[r] + bi[fc + 2 * H] + rr * (hn[r] + bh[fc + 2 * H]));
            if (f < H) {
                float hprev = hin[(n0 + r) * H + f];
                float hnew = (1.f - zz) * nn + zz * hprev;
                hout[(n0 + r) * H + f] = hnew;
                hh[(size_t)(n0 + r) * HP + f] = (_Float16)hnew;
            }
        }
    }
}

// ---------- pool: batch is sorted -> binary search graph ranges ----------
__global__ void pool_seg(const float* __restrict__ h, const int* __restrict__ batch,
                         float* __restrict__ g) {
    int wid = (blockIdx.x * blockDim.x + threadIdx.x) >> 6;
    int lane = threadIdx.x & 63;
    if (wid >= NG) return;
    int lo = 0, hi = NN;
    while (lo < hi) { int mid = (lo + hi) >> 1; if (batch[mid] < wid) lo = mid + 1; else hi = mid; }
    int beg = lo;
    lo = beg; hi = NN;
    while (lo < hi) { int mid = (lo + hi) >> 1; if (batch[mid] < wid + 1) lo = mid + 1; else hi = mid; }
    int end = lo;
    float acc = 0.f;
    if (lane < H) {
        for (int n = beg; n < end; ++n) acc += h[n * H + lane];
        g[wid * H + lane] = acc;
    }
}

// ---------- dense: out = act(in @ W^T + b), RB-row register blocking ----------
template <int K, int ACT, int RB>
__global__ void dense_rb(const float* __restrict__ in, const float* __restrict__ W,
                         const float* __restrict__ b, float* __restrict__ out,
                         int rows, int cols) {
    int t = blockIdx.x * blockDim.x + threadIdx.x;
    int ngroups = rows / RB;
    if (t >= ngroups * cols) return;
    int c = t % cols;
    int r0 = (t / cols) * RB;
    float acc[RB];
#pragma unroll
    for (int r = 0; r < RB; ++r) acc[r] = b[c];
    const float* wr = W + (size_t)c * K;
    for (int k = 0; k < K; ++k) {
        float w = wr[k];
#pragma unroll
        for (int r = 0; r < RB; ++r) acc[r] += in[(r0 + r) * K + k] * w;
    }
#pragma unroll
    for (int r = 0; r < RB; ++r) {
        float v = acc[r];
        v = (ACT == 0) ? fmaxf(v, 0.f) : 1.f / (1.f + expf(-v));
        out[(r0 + r) * cols + c] = v;
    }
}

static inline size_t rnd256(size_t x) { return (x + 255) & ~(size_t)255; }

extern "C" void kernel_launch(void* const* d_in, const int* in_sizes, int n_in,
                              void* d_out, int out_size, void* d_ws, size_t ws_size,
                              hipStream_t stream) {
    const float* x     = (const float*)d_in[0];
    const int*   ei    = (const int*)d_in[1];
    const int*   batch = (const int*)d_in[2];
    const float* W     = (const float*)d_in[3];
    const float* W_ih  = (const float*)d_in[4];
    const float* W_hh  = (const float*)d_in[5];
    const float* b_ih  = (const float*)d_in[6];
    const float* b_hh  = (const float*)d_in[7];
    const float* W1    = (const float*)d_in[8];
    const float* b1    = (const float*)d_in[9];
    const float* W2    = (const float*)d_in[10];
    const float* b2    = (const float*)d_in[11];
    const float* W3    = (const float*)d_in[12];
    const float* b3    = (const float*)d_in[13];
    const float* Wp    = (const float*)d_in[14];
    const float* bp    = (const float*)d_in[15];
    float* out = (float*)d_out;

    const int* src = ei;
    const int* dst = ei + NE;

    char* ws = (char*)d_ws;
    float*    aggH = (float*)ws;    ws += rnd256((size_t)NN * H * sizeof(float));
    float*    ha   = (float*)ws;    ws += rnd256((size_t)NN * H * sizeof(float));
    float*    hb   = (float*)ws;    ws += rnd256((size_t)NN * H * sizeof(float));
    _Float16* hh   = (_Float16*)ws; ws += rnd256((size_t)NN * HP * sizeof(_Float16));
    int*   eadj  = (int*)ws;   ws += rnd256((size_t)NE * sizeof(int));
    int*   deg   = (int*)ws;   ws += rnd256((size_t)NN * sizeof(int));
    int*   tmp   = (int*)ws;   ws += rnd256((size_t)NN * sizeof(int));
    int*   rowp  = (int*)ws;   ws += rnd256((size_t)(NN + 1) * sizeof(int));
    int*   pos   = (int*)ws;   ws += rnd256((size_t)NN * sizeof(int));
    int*   bsum  = (int*)ws;   ws += rnd256((size_t)512 * sizeof(int));
    int*   boff  = (int*)ws;   ws += rnd256((size_t)512 * sizeof(int));
    float* Wc    = (float*)ws; ws += rnd256((size_t)5 * H * H3 * sizeof(float));
    float* g     = (float*)ws; ws += rnd256((size_t)NG * H * sizeof(float));
    float* f1    = (float*)ws; ws += rnd256((size_t)NG * FFD * sizeof(float));
    float* f2    = (float*)ws; ws += rnd256((size_t)NG * FFD * sizeof(float));
    float* f3    = (float*)ws; ws += rnd256((size_t)NG * FFD * sizeof(float));

    const int blk = 256;

    // ---- CSR build (once; reused by all 5 layers); XCD-sharded hist/fill ----
    hipMemsetAsync(deg, 0, (size_t)NN * sizeof(int), stream);
    hist_sh<<<FBLK, blk, 0, stream>>>(dst, deg);
    scan1<<<NBLK, SB, 0, stream>>>(deg, tmp, bsum);
    scan2<<<1, 512, 0, stream>>>(bsum, boff);
    scan3<<<(NN + 1 + blk - 1) / blk, blk, 0, stream>>>(deg, tmp, boff, rowp);
    copy_pos<<<(NN + blk - 1) / blk, blk, 0, stream>>>(rowp, pos);
    fill_sh<<<FBLK, blk, 0, stream>>>(src, dst, pos, eadj);

    // ---- fold W[l] into GRU input weights; seed fp16 table ----
    wc_build<<<(5 * H * H3 + blk - 1) / blk, blk, 0, stream>>>(W, W_ih, Wc);
    conv_x<<<(NN * HP + blk - 1) / blk, blk, 0, stream>>>(x, hh);

    // ---- 5 GGC layers ----
    const int grid_gather = (NN * 64 + blk - 1) / blk; // one wave per node
    const float* hin = x;
    float* hout = ha;
    for (int l = 0; l < 5; ++l) {
        gather<<<grid_gather, blk, 0, stream>>>(hh, rowp, eadj, aggH);
        gru_f<<<GRU_BLOCKS, blk, 0, stream>>>(aggH, hin, Wc + (size_t)l * H * H3,
                                              W_hh, b_ih, b_hh, hout, hh);
        hin = hout;
        hout = (hout == ha) ? hb : ha;
    }

    // ---- pool (batch sorted -> binary search ranges) ----
    pool_seg<<<(NG * 64 + blk - 1) / blk, blk, 0, stream>>>(hin, batch, g);

    // ---- MLP head ----
    dense_rb<H, 0, 4><<<((NG / 4) * FFD + blk - 1) / blk, blk, 0, stream>>>(g,  W1, b1, f1, NG, FFD);
    dense_rb<FFD, 0, 4><<<((NG / 4) * FFD + blk - 1) / blk, blk, 0, stream>>>(f1, W2, b2, f2, NG, FFD);
    dense_rb<FFD, 0, 4><<<((NG / 4) * FFD + blk - 1) / blk, blk, 0, stream>>>(f2, W3, b3, f3, NG, FFD);
    dense_rb<FFD, 1, 4><<<((NG / 4) * NLB + blk - 1) / blk, blk, 0, stream>>>(f3, Wp, bp, out, NG, NLB);
}

// Round 5
// 1056.243 us; speedup vs baseline: 5.0882x; 1.0934x over previous
//
#include <hip/hip_runtime.h>
#include <math.h>

#define H 43
#define H3 129
#define HP 64                     // padded row (fp16) -> 128B, line-aligned
#define NN 100000
#define NE 1600000
#define NG 2048
#define FFD 392
#define NLB 138
#define SB 256                    // scan block size
#define NBLK ((NN + SB - 1) / SB) // 391
#define RG 8                      // nodes per wave in gru
#define GRU_BLOCKS 768
#define NGRP ((NN + RG - 1) / RG) // 12500
#define NXCD 8
#define RANGE (NN / NXCD)         // 12500 dst-nodes per XCD shard
#define FBLK 2048                 // fill/hist grid: 256 blocks per shard
#define CHUNK ((NE + 255) / 256)  // 6250 edges per block-chunk

// ---------- CSR build (XCD-sharded: group g = blockIdx&7 owns dst range g) ----------
__global__ void hist_sh(const int* __restrict__ dst, int* __restrict__ deg) {
    int g = blockIdx.x & (NXCD - 1);
    int i = blockIdx.x >> 3;
    int lo = g * RANGE, hi = lo + RANGE;
    int e0 = i * CHUNK;
    int e1 = min(NE, e0 + CHUNK);
    for (int e = e0 + threadIdx.x; e < e1; e += blockDim.x) {
        int d = dst[e];
        if (d >= lo && d < hi) atomicAdd(&deg[d], 1);
    }
}

__global__ void fill_sh(const int* __restrict__ src, const int* __restrict__ dst,
                        int* __restrict__ pos, int* __restrict__ eadj) {
    int g = blockIdx.x & (NXCD - 1);
    int i = blockIdx.x >> 3;
    int lo = g * RANGE, hi = lo + RANGE;
    int e0 = i * CHUNK;
    int e1 = min(NE, e0 + CHUNK);
    for (int e = e0 + threadIdx.x; e < e1; e += blockDim.x) {
        int d = dst[e];
        if (d >= lo && d < hi) {
            int slot = atomicAdd(&pos[d], 1);
            eadj[slot] = src[e];
        }
    }
}

__global__ void scan1(const int* __restrict__ deg, int* __restrict__ tmp, int* __restrict__ bsum) {
    __shared__ int s[SB];
    int i = blockIdx.x * SB + threadIdx.x;
    int v = (i < NN) ? deg[i] : 0;
    s[threadIdx.x] = v;
    __syncthreads();
    for (int off = 1; off < SB; off <<= 1) {
        int t = (threadIdx.x >= (unsigned)off) ? s[threadIdx.x - off] : 0;
        __syncthreads();
        s[threadIdx.x] += t;
        __syncthreads();
    }
    if (i < NN) tmp[i] = s[threadIdx.x];
    if (threadIdx.x == SB - 1) bsum[blockIdx.x] = s[SB - 1];
}

__global__ void scan2(const int* __restrict__ bsum, int* __restrict__ boff) {
    __shared__ int s[512];
    int v = (threadIdx.x < NBLK) ? bsum[threadIdx.x] : 0;
    s[threadIdx.x] = v;
    __syncthreads();
    for (int off = 1; off < 512; off <<= 1) {
        int t = (threadIdx.x >= (unsigned)off) ? s[threadIdx.x - off] : 0;
        __syncthreads();
        s[threadIdx.x] += t;
        __syncthreads();
    }
    boff[threadIdx.x] = s[threadIdx.x] - v; // exclusive
}

__global__ void scan3(const int* __restrict__ deg, const int* __restrict__ tmp,
                      const int* __restrict__ boff, int* __restrict__ rowptr) {
    int i = blockIdx.x * blockDim.x + threadIdx.x;
    if (i < NN) rowptr[i] = tmp[i] - deg[i] + boff[i / SB];
    if (i == NN) rowptr[NN] = NE;
}

__global__ void copy_pos(const int* __restrict__ rowptr, int* __restrict__ pos) {
    int i = blockIdx.x * blockDim.x + threadIdx.x;
    if (i < NN) pos[i] = rowptr[i];
}

// ---------- Wc[l] = W[l] @ W_ih^T  -> [5][43][129] ----------
__global__ void wc_build(const float* __restrict__ W, const float* __restrict__ W_ih,
                         float* __restrict__ Wc) {
    int t = blockIdx.x * blockDim.x + threadIdx.x;
    if (t >= 5 * H * H3) return;
    int l = t / (H * H3);
    int rem = t % (H * H3);
    int k = rem / H3, j = rem % H3;
    const float* Wl = W + l * H * H;
    float acc = 0.f;
#pragma unroll
    for (int c = 0; c < H; ++c) acc += Wl[k * H + c] * W_ih[j * H + c];
    Wc[t] = acc;
}

// ---------- generic transpose: At[j*R + i] = A[i*C + j] ----------
__global__ void tr_mat(const float* __restrict__ A, float* __restrict__ At, int R, int C) {
    int t = blockIdx.x * blockDim.x + threadIdx.x;
    if (t >= R * C) return;
    int i = t / C, j = t % C;
    At[(size_t)j * R + i] = A[t];
}

// ---------- seed fp16 gather table from x ----------
__global__ void conv_x(const float* __restrict__ x, _Float16* __restrict__ hh) {
    int t = blockIdx.x * blockDim.x + threadIdx.x;
    if (t >= NN * HP) return;
    int n = t >> 6, f = t & (HP - 1);
    hh[t] = (f < H) ? (_Float16)x[n * H + f] : (_Float16)0.f;
}

// ---------- aggH[n] = sum over incoming edges of hh[src] (fp16 rows, f32 acc) ----------
__global__ __launch_bounds__(256) void gather(const _Float16* __restrict__ hh,
                                              const int* __restrict__ rowptr,
                                              const int* __restrict__ eadj,
                                              float* __restrict__ aggH) {
    int wid = (blockIdx.x * blockDim.x + threadIdx.x) >> 6;
    int lane = threadIdx.x & 63;
    if (wid >= NN) return;
    int beg = rowptr[wid], end = rowptr[wid + 1];
    int fc = (lane < H) ? lane : 0;
    float acc = 0.f;
    for (int base = beg; base < end; base += 64) {
        int cnt = min(64, end - base);
        int idx = (base + lane < end) ? eadj[base + lane] : 0;
        int r = 0;
        for (; r + 8 <= cnt; r += 8) {
            int s0 = __shfl(idx, r + 0), s1 = __shfl(idx, r + 1);
            int s2 = __shfl(idx, r + 2), s3 = __shfl(idx, r + 3);
            int s4 = __shfl(idx, r + 4), s5 = __shfl(idx, r + 5);
            int s6 = __shfl(idx, r + 6), s7 = __shfl(idx, r + 7);
            float v0 = (float)hh[(size_t)s0 * HP + fc];
            float v1 = (float)hh[(size_t)s1 * HP + fc];
            float v2 = (float)hh[(size_t)s2 * HP + fc];
            float v3 = (float)hh[(size_t)s3 * HP + fc];
            float v4 = (float)hh[(size_t)s4 * HP + fc];
            float v5 = (float)hh[(size_t)s5 * HP + fc];
            float v6 = (float)hh[(size_t)s6 * HP + fc];
            float v7 = (float)hh[(size_t)s7 * HP + fc];
            acc += ((v0 + v1) + (v2 + v3)) + ((v4 + v5) + (v6 + v7));
        }
        if (r + 4 <= cnt) {
            int s0 = __shfl(idx, r + 0), s1 = __shfl(idx, r + 1);
            int s2 = __shfl(idx, r + 2), s3 = __shfl(idx, r + 3);
            float v0 = (float)hh[(size_t)s0 * HP + fc];
            float v1 = (float)hh[(size_t)s1 * HP + fc];
            float v2 = (float)hh[(size_t)s2 * HP + fc];
            float v3 = (float)hh[(size_t)s3 * HP + fc];
            acc += (v0 + v1) + (v2 + v3);
            r += 4;
        }
        for (; r < cnt; ++r) {
            int s = __shfl(idx, r);
            acc += (float)hh[(size_t)s * HP + fc];
        }
    }
    if (lane < H) aggH[wid * H + lane] = acc;
}

// ---------- fused GRU:  gi = aggH@Wc + b_ih ; gh = h@W_hh^T + b_hh ----------
// Also writes the fp16 gather table for the next layer.
__global__ __launch_bounds__(256) void gru_f(const float* __restrict__ aggH,
                                             const float* __restrict__ hin,
                                             const float* __restrict__ Wc_l,
                                             const float* __restrict__ W_hh,
                                             const float* __restrict__ b_ih,
                                             const float* __restrict__ b_hh,
                                             float* __restrict__ hout,
                                             _Float16* __restrict__ hh) {
    __shared__ float Wcs[H * H3]; // [k][j] 43x129
    __shared__ float Whs[H3 * H]; // [j][k] 129x43
    __shared__ float bi[H3], bh[H3];
    for (int i = threadIdx.x; i < H * H3; i += 256) {
        Wcs[i] = Wc_l[i];
        Whs[i] = W_hh[i];
    }
    for (int i = threadIdx.x; i < H3; i += 256) {
        bi[i] = b_ih[i];
        bh[i] = b_hh[i];
    }
    __syncthreads();

    int lane = threadIdx.x & 63;
    int f = lane;
    int fc = (f < H) ? f : 0; // safe index for idle lanes
    int wid = (blockIdx.x * blockDim.x + threadIdx.x) >> 6;
    const int nwaves = GRU_BLOCKS * 4;

    for (int grp = wid; grp < NGRP; grp += nwaves) {
        int n0 = grp * RG;
        float ir[RG], iz[RG], in_[RG], hr_[RG], hz[RG], hn[RG];
#pragma unroll
        for (int r = 0; r < RG; ++r) { ir[r] = iz[r] = in_[r] = hr_[r] = hz[r] = hn[r] = 0.f; }

        for (int k = 0; k < H; ++k) {
            float wcr = Wcs[k * H3 + fc];
            float wcz = Wcs[k * H3 + fc + H];
            float wcn = Wcs[k * H3 + fc + 2 * H];
            float whr = Whs[fc * H + k];
            float whz = Whs[(fc + H) * H + k];
            float whn = Whs[(fc + 2 * H) * H + k];
#pragma unroll
            for (int r = 0; r < RG; ++r) {
                float a = aggH[(n0 + r) * H + k];
                float hh2 = hin[(n0 + r) * H + k];
                ir[r] += a * wcr;
                iz[r] += a * wcz;
                in_[r] += a * wcn;
                hr_[r] += hh2 * whr;
                hz[r] += hh2 * whz;
                hn[r] += hh2 * whn;
            }
        }
#pragma unroll
        for (int r = 0; r < RG; ++r) {
            float gr = ir[r] + bi[fc] + hr_[r] + bh[fc];
            float gz = iz[r] + bi[fc + H] + hz[r] + bh[fc + H];
            float rr = 1.f / (1.f + expf(-gr));
            float zz = 1.f / (1.f + expf(-gz));
            float nn = tanhf(in_[r] + bi[fc + 2 * H] + rr * (hn[r] + bh[fc + 2 * H]));
            if (f < H) {
                float hprev = hin[(n0 + r) * H + f];
                float hnew = (1.f - zz) * nn + zz * hprev;
                hout[(n0 + r) * H + f] = hnew;
                hh[(size_t)(n0 + r) * HP + f] = (_Float16)hnew;
            }
        }
    }
}

// ---------- pool: batch is sorted -> binary search graph ranges ----------
__global__ void pool_seg(const float* __restrict__ h, const int* __restrict__ batch,
                         float* __restrict__ g) {
    int wid = (blockIdx.x * blockDim.x + threadIdx.x) >> 6;
    int lane = threadIdx.x & 63;
    if (wid >= NG) return;
    int lo = 0, hi = NN;
    while (lo < hi) { int mid = (lo + hi) >> 1; if (batch[mid] < wid) lo = mid + 1; else hi = mid; }
    int beg = lo;
    lo = beg; hi = NN;
    while (lo < hi) { int mid = (lo + hi) >> 1; if (batch[mid] < wid + 1) lo = mid + 1; else hi = mid; }
    int end = lo;
    float acc = 0.f;
    if (lane < H) {
        for (int n = beg; n < end; ++n) acc += h[n * H + lane];
        g[wid * H + lane] = acc;
    }
}

// ---------- dense with TRANSPOSED weights: out = act(in @ W^T + b) ----------
// Wt is [K][cols] so lane-consecutive c -> consecutive addresses (coalesced).
// in-loads are wave-uniform (broadcast). RB rows per thread amortize Wt reads.
template <int K, int ACT, int RB>
__global__ void dense_t(const float* __restrict__ in, const float* __restrict__ Wt,
                        const float* __restrict__ b, float* __restrict__ out,
                        int rows, int cols) {
    int t = blockIdx.x * blockDim.x + threadIdx.x;
    int ngroups = rows / RB;
    if (t >= ngroups * cols) return;
    int c = t % cols;
    int r0 = (t / cols) * RB;
    float acc[RB];
#pragma unroll
    for (int r = 0; r < RB; ++r) acc[r] = b[c];
#pragma unroll 4
    for (int k = 0; k < K; ++k) {
        float w = Wt[(size_t)k * cols + c];
#pragma unroll
        for (int r = 0; r < RB; ++r) acc[r] += in[(r0 + r) * K + k] * w;
    }
#pragma unroll
    for (int r = 0; r < RB; ++r) {
        float v = acc[r];
        v = (ACT == 0) ? fmaxf(v, 0.f) : 1.f / (1.f + expf(-v));
        out[(r0 + r) * cols + c] = v;
    }
}

static inline size_t rnd256(size_t x) { return (x + 255) & ~(size_t)255; }

extern "C" void kernel_launch(void* const* d_in, const int* in_sizes, int n_in,
                              void* d_out, int out_size, void* d_ws, size_t ws_size,
                              hipStream_t stream) {
    const float* x     = (const float*)d_in[0];
    const int*   ei    = (const int*)d_in[1];
    const int*   batch = (const int*)d_in[2];
    const float* W     = (const float*)d_in[3];
    const float* W_ih  = (const float*)d_in[4];
    const float* W_hh  = (const float*)d_in[5];
    const float* b_ih  = (const float*)d_in[6];
    const float* b_hh  = (const float*)d_in[7];
    const float* W1    = (const float*)d_in[8];
    const float* b1    = (const float*)d_in[9];
    const float* W2    = (const float*)d_in[10];
    const float* b2    = (const float*)d_in[11];
    const float* W3    = (const float*)d_in[12];
    const float* b3    = (const float*)d_in[13];
    const float* Wp    = (const float*)d_in[14];
    const float* bp    = (const float*)d_in[15];
    float* out = (float*)d_out;

    const int* src = ei;
    const int* dst = ei + NE;

    char* ws = (char*)d_ws;
    float*    aggH = (float*)ws;    ws += rnd256((size_t)NN * H * sizeof(float));
    float*    ha   = (float*)ws;    ws += rnd256((size_t)NN * H * sizeof(float));
    float*    hb   = (float*)ws;    ws += rnd256((size_t)NN * H * sizeof(float));
    _Float16* hh   = (_Float16*)ws; ws += rnd256((size_t)NN * HP * sizeof(_Float16));
    int*   eadj  = (int*)ws;   ws += rnd256((size_t)NE * sizeof(int));
    int*   deg   = (int*)ws;   ws += rnd256((size_t)NN * sizeof(int));
    int*   tmp   = (int*)ws;   ws += rnd256((size_t)NN * sizeof(int));
    int*   rowp  = (int*)ws;   ws += rnd256((size_t)(NN + 1) * sizeof(int));
    int*   pos   = (int*)ws;   ws += rnd256((size_t)NN * sizeof(int));
    int*   bsum  = (int*)ws;   ws += rnd256((size_t)512 * sizeof(int));
    int*   boff  = (int*)ws;   ws += rnd256((size_t)512 * sizeof(int));
    float* Wc    = (float*)ws; ws += rnd256((size_t)5 * H * H3 * sizeof(float));
    float* g     = (float*)ws; ws += rnd256((size_t)NG * H * sizeof(float));
    float* f1    = (float*)ws; ws += rnd256((size_t)NG * FFD * sizeof(float));
    float* f2    = (float*)ws; ws += rnd256((size_t)NG * FFD * sizeof(float));
    float* f3    = (float*)ws; ws += rnd256((size_t)NG * FFD * sizeof(float));
    float* W1t   = (float*)ws; ws += rnd256((size_t)H * FFD * sizeof(float));
    float* W2t   = (float*)ws; ws += rnd256((size_t)FFD * FFD * sizeof(float));
    float* W3t   = (float*)ws; ws += rnd256((size_t)FFD * FFD * sizeof(float));
    float* Wpt   = (float*)ws; ws += rnd256((size_t)FFD * NLB * sizeof(float));

    const int blk = 256;

    // ---- CSR build (once; reused by all 5 layers); XCD-sharded hist/fill ----
    hipMemsetAsync(deg, 0, (size_t)NN * sizeof(int), stream);
    hist_sh<<<FBLK, blk, 0, stream>>>(dst, deg);
    scan1<<<NBLK, SB, 0, stream>>>(deg, tmp, bsum);
    scan2<<<1, 512, 0, stream>>>(bsum, boff);
    scan3<<<(NN + 1 + blk - 1) / blk, blk, 0, stream>>>(deg, tmp, boff, rowp);
    copy_pos<<<(NN + blk - 1) / blk, blk, 0, stream>>>(rowp, pos);
    fill_sh<<<FBLK, blk, 0, stream>>>(src, dst, pos, eadj);

    // ---- fold W[l] into GRU input weights; seed fp16 table; transpose MLP weights ----
    wc_build<<<(5 * H * H3 + blk - 1) / blk, blk, 0, stream>>>(W, W_ih, Wc);
    conv_x<<<(NN * HP + blk - 1) / blk, blk, 0, stream>>>(x, hh);
    tr_mat<<<(FFD * H + blk - 1) / blk, blk, 0, stream>>>(W1, W1t, FFD, H);
    tr_mat<<<(FFD * FFD + blk - 1) / blk, blk, 0, stream>>>(W2, W2t, FFD, FFD);
    tr_mat<<<(FFD * FFD + blk - 1) / blk, blk, 0, stream>>>(W3, W3t, FFD, FFD);
    tr_mat<<<(NLB * FFD + blk - 1) / blk, blk, 0, stream>>>(Wp, Wpt, NLB, FFD);

    // ---- 5 GGC layers ----
    const int grid_gather = (NN * 64 + blk - 1) / blk; // one wave per node
    const float* hin = x;
    float* hout = ha;
    for (int l = 0; l < 5; ++l) {
        gather<<<grid_gather, blk, 0, stream>>>(hh, rowp, eadj, aggH);
        gru_f<<<GRU_BLOCKS, blk, 0, stream>>>(aggH, hin, Wc + (size_t)l * H * H3,
                                              W_hh, b_ih, b_hh, hout, hh);
        hin = hout;
        hout = (hout == ha) ? hb : ha;
    }

    // ---- pool (batch sorted -> binary search ranges) ----
    pool_seg<<<(NG * 64 + blk - 1) / blk, blk, 0, stream>>>(hin, batch, g);

    // ---- MLP head (transposed weights, coalesced) ----
    dense_t<H, 0, 8><<<((NG / 8) * FFD + blk - 1) / blk, blk, 0, stream>>>(g,  W1t, b1, f1, NG, FFD);
    dense_t<FFD, 0, 8><<<((NG / 8) * FFD + blk - 1) / blk, blk, 0, stream>>>(f1, W2t, b2, f2, NG, FFD);
    dense_t<FFD, 0, 8><<<((NG / 8) * FFD + blk - 1) / blk, blk, 0, stream>>>(f2, W3t, b3, f3, NG, FFD);
    dense_t<FFD, 1, 8><<<((NG / 8) * NLB + blk - 1) / blk, blk, 0, stream>>>(f3, Wpt, bp, out, NG, NLB);
}

// Round 6
// 946.368 us; speedup vs baseline: 5.6789x; 1.1161x over previous
//
#include <hip/hip_runtime.h>
#include <math.h>

#define H 43
#define H3 129
#define HP 64                     // padded fp16 row -> 128B
#define NN 100000
#define NE 1600000
#define NG 2048
#define FFD 392
#define NLB 138
#define SB 256
#define NBLK ((NN + SB - 1) / SB) // 391
#define NXCD 8
#define SHARD 12544               // 196 * 64 node-shard per XCD; 8*12544 >= NN
#define TILES 196                 // 64-node tiles per shard
#define GT_BLOCKS (NXCD * TILES)  // 1568 (gru / conv grid)
#define GA_BLOCKS (NXCD * (SHARD / 4)) // 25088 (gather grid, 4 nodes/block)
#define FBLK 2048
#define CHUNK ((NE + 255) / 256)  // 6250

// ---------- CSR build (XCD-sharded by dst range) ----------
__global__ void hist_sh(const int* __restrict__ dst, int* __restrict__ deg) {
    int g = blockIdx.x & (NXCD - 1);
    int i = blockIdx.x >> 3;
    int lo = g * SHARD, hi = min(lo + SHARD, NN);
    int e0 = i * CHUNK, e1 = min(NE, e0 + CHUNK);
    for (int e = e0 + threadIdx.x; e < e1; e += blockDim.x) {
        int d = dst[e];
        if (d >= lo && d < hi) atomicAdd(&deg[d], 1);
    }
}

__global__ void fill_sh(const int* __restrict__ src, const int* __restrict__ dst,
                        int* __restrict__ pos, int* __restrict__ eadj) {
    int g = blockIdx.x & (NXCD - 1);
    int i = blockIdx.x >> 3;
    int lo = g * SHARD, hi = min(lo + SHARD, NN);
    int e0 = i * CHUNK, e1 = min(NE, e0 + CHUNK);
    for (int e = e0 + threadIdx.x; e < e1; e += blockDim.x) {
        int d = dst[e];
        if (d >= lo && d < hi) {
            int slot = atomicAdd(&pos[d], 1);
            eadj[slot] = src[e];
        }
    }
}

__global__ void scan1(const int* __restrict__ deg, int* __restrict__ tmp, int* __restrict__ bsum) {
    __shared__ int s[SB];
    int i = blockIdx.x * SB + threadIdx.x;
    int v = (i < NN) ? deg[i] : 0;
    s[threadIdx.x] = v;
    __syncthreads();
    for (int off = 1; off < SB; off <<= 1) {
        int t = (threadIdx.x >= (unsigned)off) ? s[threadIdx.x - off] : 0;
        __syncthreads();
        s[threadIdx.x] += t;
        __syncthreads();
    }
    if (i < NN) tmp[i] = s[threadIdx.x];
    if (threadIdx.x == SB - 1) bsum[blockIdx.x] = s[SB - 1];
}

__global__ void scan2(const int* __restrict__ bsum, int* __restrict__ boff) {
    __shared__ int s[512];
    int v = (threadIdx.x < NBLK) ? bsum[threadIdx.x] : 0;
    s[threadIdx.x] = v;
    __syncthreads();
    for (int off = 1; off < 512; off <<= 1) {
        int t = (threadIdx.x >= (unsigned)off) ? s[threadIdx.x - off] : 0;
        __syncthreads();
        s[threadIdx.x] += t;
        __syncthreads();
    }
    boff[threadIdx.x] = s[threadIdx.x] - v; // exclusive
}

__global__ void scan3(const int* __restrict__ deg, const int* __restrict__ tmp,
                      const int* __restrict__ boff, int* __restrict__ rowptr) {
    int i = blockIdx.x * blockDim.x + threadIdx.x;
    if (i < NN) rowptr[i] = tmp[i] - deg[i] + boff[i / SB];
    if (i == NN) rowptr[NN] = NE;
}

__global__ void copy_pos(const int* __restrict__ rowptr, int* __restrict__ pos) {
    int i = blockIdx.x * blockDim.x + threadIdx.x;
    if (i < NN) pos[i] = rowptr[i];
}

// ---------- Wc[l] = W[l] @ W_ih^T -> [5][43][129] ----------
__global__ void wc_build(const float* __restrict__ W, const float* __restrict__ W_ih,
                         float* __restrict__ Wc) {
    int t = blockIdx.x * blockDim.x + threadIdx.x;
    if (t >= 5 * H * H3) return;
    int l = t / (H * H3);
    int rem = t % (H * H3);
    int k = rem / H3, j = rem % H3;
    const float* Wl = W + l * H * H;
    float acc = 0.f;
#pragma unroll
    for (int c = 0; c < H; ++c) acc += Wl[k * H + c] * W_ih[j * H + c];
    Wc[t] = acc;
}

// ---------- generic transpose: At[j*R + i] = A[i*C + j] ----------
__global__ void tr_mat(const float* __restrict__ A, float* __restrict__ At, int R, int C) {
    int t = blockIdx.x * blockDim.x + threadIdx.x;
    if (t >= R * C) return;
    int i = t / C, j = t % C;
    At[(size_t)j * R + i] = A[t];
}

// ---------- seed: hTb = x^T (feature-major), hh = fp16 padded rows ----------
__global__ void conv_xT(const float* __restrict__ x, float* __restrict__ hT,
                        _Float16* __restrict__ hh) {
    int g = blockIdx.x & (NXCD - 1);
    int t = blockIdx.x >> 3;
    int n0 = g * SHARD + t * 64;
    for (int i = threadIdx.x; i < 64 * H; i += 256) {
        int nl = i / H, f = i % H;
        int n = n0 + nl;
        if (n < NN) hT[f * NN + n] = x[n * H + f];
    }
    for (int i = threadIdx.x; i < 64 * HP; i += 256) {
        int nl = i >> 6, f = i & (HP - 1);
        int n = n0 + nl;
        if (n < NN) hh[(size_t)n * HP + f] = (f < H) ? (_Float16)x[n * H + f] : (_Float16)0.f;
    }
}

// ---------- gather: aggT[f][n] = sum over incoming edges of hh[src][f] ----------
__global__ __launch_bounds__(256) void gather_t(const _Float16* __restrict__ hh,
                                                const int* __restrict__ rowptr,
                                                const int* __restrict__ eadj,
                                                float* __restrict__ aggT) {
    int g = blockIdx.x & (NXCD - 1);
    int i = blockIdx.x >> 3;
    int wid = g * SHARD + i * 4 + (threadIdx.x >> 6);
    int lane = threadIdx.x & 63;
    if (wid >= NN) return;
    int beg = rowptr[wid], end = rowptr[wid + 1];
    int fc = (lane < H) ? lane : 0;
    float acc = 0.f;
    for (int base = beg; base < end; base += 64) {
        int cnt = min(64, end - base);
        int idx = (base + lane < end) ? eadj[base + lane] : 0;
        int r = 0;
        for (; r + 8 <= cnt; r += 8) {
            int s0 = __shfl(idx, r + 0), s1 = __shfl(idx, r + 1);
            int s2 = __shfl(idx, r + 2), s3 = __shfl(idx, r + 3);
            int s4 = __shfl(idx, r + 4), s5 = __shfl(idx, r + 5);
            int s6 = __shfl(idx, r + 6), s7 = __shfl(idx, r + 7);
            float v0 = (float)hh[(size_t)s0 * HP + fc];
            float v1 = (float)hh[(size_t)s1 * HP + fc];
            float v2 = (float)hh[(size_t)s2 * HP + fc];
            float v3 = (float)hh[(size_t)s3 * HP + fc];
            float v4 = (float)hh[(size_t)s4 * HP + fc];
            float v5 = (float)hh[(size_t)s5 * HP + fc];
            float v6 = (float)hh[(size_t)s6 * HP + fc];
            float v7 = (float)hh[(size_t)s7 * HP + fc];
            acc += ((v0 + v1) + (v2 + v3)) + ((v4 + v5) + (v6 + v7));
        }
        if (r + 4 <= cnt) {
            int s0 = __shfl(idx, r + 0), s1 = __shfl(idx, r + 1);
            int s2 = __shfl(idx, r + 2), s3 = __shfl(idx, r + 3);
            float v0 = (float)hh[(size_t)s0 * HP + fc];
            float v1 = (float)hh[(size_t)s1 * HP + fc];
            float v2 = (float)hh[(size_t)s2 * HP + fc];
            float v3 = (float)hh[(size_t)s3 * HP + fc];
            acc += (v0 + v1) + (v2 + v3);
            r += 4;
        }
        for (; r < cnt; ++r) {
            int s = __shfl(idx, r);
            acc += (float)hh[(size_t)s * HP + fc];
        }
    }
    if (lane < H) aggT[lane * NN + wid] = acc;
}

// ---------- GRU, node-per-lane, feature-major ----------
// Block = 64 nodes; wave w computes features [w*11, w*11+11) (last wave 10).
// All data loads coalesced; weights/biases wave-uniform -> scalar loads.
__global__ __launch_bounds__(256) void gru_t(const float* __restrict__ aggT,
                                             const float* __restrict__ hinT,
                                             const float* __restrict__ Wc_l,
                                             const float* __restrict__ Wht,
                                             const float* __restrict__ b_ih,
                                             const float* __restrict__ b_hh,
                                             float* __restrict__ houtT,
                                             _Float16* __restrict__ hh) {
    int g = blockIdx.x & (NXCD - 1);
    int t = blockIdx.x >> 3;
    int n0 = g * SHARD + t * 64;
    int lane = threadIdx.x & 63;
    int w = __builtin_amdgcn_readfirstlane(threadIdx.x >> 6);
    int fb = w * 11;
    int n = n0 + lane;
    bool act = (n < NN);
    int nc = act ? n : (NN - 1);

    float air[11], aiz[11], ain[11], ahr[11], ahz[11], ahn[11];
#pragma unroll
    for (int j = 0; j < 11; ++j) { air[j] = aiz[j] = ain[j] = ahr[j] = ahz[j] = ahn[j] = 0.f; }

    for (int k = 0; k < H; ++k) {
        float a = aggT[k * NN + nc];
        float hv = hinT[k * NN + nc];
        const float* wc = Wc_l + k * H3 + fb;
        const float* wh = Wht + k * H3 + fb;
#pragma unroll
        for (int j = 0; j < 11; ++j) {
            air[j] += a * wc[j];
            aiz[j] += a * wc[H + j];
            ain[j] += a * wc[2 * H + j];
            ahr[j] += hv * wh[j];
            ahz[j] += hv * wh[H + j];
            ahn[j] += hv * wh[2 * H + j];
        }
    }

#pragma unroll
    for (int j = 0; j < 11; ++j) {
        int f = fb + j;
        if (f < H) {
            float gr = air[j] + b_ih[f] + ahr[j] + b_hh[f];
            float gz = aiz[j] + b_ih[H + f] + ahz[j] + b_hh[H + f];
            float r = 1.f / (1.f + expf(-gr));
            float z = 1.f / (1.f + expf(-gz));
            float nv = tanhf(ain[j] + b_ih[2 * H + f] + r * (ahn[j] + b_hh[2 * H + f]));
            float hp = hinT[f * NN + nc];
            float hnew = (1.f - z) * nv + z * hp;
            if (act) {
                houtT[f * NN + n] = hnew;
                hh[(size_t)n * HP + f] = (_Float16)hnew;
            }
        }
    }
}

// ---------- pool over sorted batch, reading feature-major hT ----------
__global__ void pool_T(const float* __restrict__ hT, const int* __restrict__ batch,
                       float* __restrict__ gout) {
    int wid = (blockIdx.x * blockDim.x + threadIdx.x) >> 6;
    int lane = threadIdx.x & 63;
    if (wid >= NG) return;
    int lo = 0, hi = NN;
    while (lo < hi) { int mid = (lo + hi) >> 1; if (batch[mid] < wid) lo = mid + 1; else hi = mid; }
    int beg = lo;
    lo = beg; hi = NN;
    while (lo < hi) { int mid = (lo + hi) >> 1; if (batch[mid] < wid + 1) lo = mid + 1; else hi = mid; }
    int end = lo;
    if (lane < H) {
        float acc = 0.f;
        const float* row = hT + (size_t)lane * NN;
        for (int nn2 = beg; nn2 < end; ++nn2) acc += row[nn2];
        gout[wid * H + lane] = acc;
    }
}

// ---------- dense with transposed weights ----------
template <int K, int ACT, int RB>
__global__ void dense_t(const float* __restrict__ in, const float* __restrict__ Wt,
                        const float* __restrict__ b, float* __restrict__ out,
                        int rows, int cols) {
    int t = blockIdx.x * blockDim.x + threadIdx.x;
    int ngroups = rows / RB;
    if (t >= ngroups * cols) return;
    int c = t % cols;
    int r0 = (t / cols) * RB;
    float acc[RB];
#pragma unroll
    for (int r = 0; r < RB; ++r) acc[r] = b[c];
#pragma unroll 4
    for (int k = 0; k < K; ++k) {
        float w = Wt[(size_t)k * cols + c];
#pragma unroll
        for (int r = 0; r < RB; ++r) acc[r] += in[(r0 + r) * K + k] * w;
    }
#pragma unroll
    for (int r = 0; r < RB; ++r) {
        float v = acc[r];
        v = (ACT == 0) ? fmaxf(v, 0.f) : 1.f / (1.f + expf(-v));
        out[(r0 + r) * cols + c] = v;
    }
}

static inline size_t rnd256(size_t x) { return (x + 255) & ~(size_t)255; }

extern "C" void kernel_launch(void* const* d_in, const int* in_sizes, int n_in,
                              void* d_out, int out_size, void* d_ws, size_t ws_size,
                              hipStream_t stream) {
    const float* x     = (const float*)d_in[0];
    const int*   ei    = (const int*)d_in[1];
    const int*   batch = (const int*)d_in[2];
    const float* W     = (const float*)d_in[3];
    const float* W_ih  = (const float*)d_in[4];
    const float* W_hh  = (const float*)d_in[5];
    const float* b_ih  = (const float*)d_in[6];
    const float* b_hh  = (const float*)d_in[7];
    const float* W1    = (const float*)d_in[8];
    const float* b1    = (const float*)d_in[9];
    const float* W2    = (const float*)d_in[10];
    const float* b2    = (const float*)d_in[11];
    const float* W3    = (const float*)d_in[12];
    const float* b3    = (const float*)d_in[13];
    const float* Wp    = (const float*)d_in[14];
    const float* bp    = (const float*)d_in[15];
    float* out = (float*)d_out;

    const int* src = ei;
    const int* dst = ei + NE;

    char* ws = (char*)d_ws;
    float*    aggT = (float*)ws;    ws += rnd256((size_t)H * NN * sizeof(float));
    float*    hTa  = (float*)ws;    ws += rnd256((size_t)H * NN * sizeof(float));
    float*    hTb  = (float*)ws;    ws += rnd256((size_t)H * NN * sizeof(float));
    _Float16* hh   = (_Float16*)ws; ws += rnd256((size_t)NN * HP * sizeof(_Float16));
    int*   eadj  = (int*)ws;   ws += rnd256((size_t)NE * sizeof(int));
    int*   deg   = (int*)ws;   ws += rnd256((size_t)NN * sizeof(int));
    int*   tmp   = (int*)ws;   ws += rnd256((size_t)NN * sizeof(int));
    int*   rowp  = (int*)ws;   ws += rnd256((size_t)(NN + 1) * sizeof(int));
    int*   pos   = (int*)ws;   ws += rnd256((size_t)NN * sizeof(int));
    int*   bsum  = (int*)ws;   ws += rnd256((size_t)512 * sizeof(int));
    int*   boff  = (int*)ws;   ws += rnd256((size_t)512 * sizeof(int));
    float* Wc    = (float*)ws; ws += rnd256(((size_t)5 * H * H3 + 256) * sizeof(float));
    float* Wht   = (float*)ws; ws += rnd256(((size_t)H * H3 + 256) * sizeof(float));
    float* gbuf  = (float*)ws; ws += rnd256((size_t)NG * H * sizeof(float));
    float* f1    = (float*)ws; ws += rnd256((size_t)NG * FFD * sizeof(float));
    float* f2    = (float*)ws; ws += rnd256((size_t)NG * FFD * sizeof(float));
    float* f3    = (float*)ws; ws += rnd256((size_t)NG * FFD * sizeof(float));
    float* W1t   = (float*)ws; ws += rnd256((size_t)H * FFD * sizeof(float));
    float* W2t   = (float*)ws; ws += rnd256((size_t)FFD * FFD * sizeof(float));
    float* W3t   = (float*)ws; ws += rnd256((size_t)FFD * FFD * sizeof(float));
    float* Wpt   = (float*)ws; ws += rnd256((size_t)FFD * NLB * sizeof(float));

    const int blk = 256;

    // ---- CSR build (once) ----
    hipMemsetAsync(deg, 0, (size_t)NN * sizeof(int), stream);
    hist_sh<<<FBLK, blk, 0, stream>>>(dst, deg);
    scan1<<<NBLK, SB, 0, stream>>>(deg, tmp, bsum);
    scan2<<<1, 512, 0, stream>>>(bsum, boff);
    scan3<<<(NN + 1 + blk - 1) / blk, blk, 0, stream>>>(deg, tmp, boff, rowp);
    copy_pos<<<(NN + blk - 1) / blk, blk, 0, stream>>>(rowp, pos);
    fill_sh<<<FBLK, blk, 0, stream>>>(src, dst, pos, eadj);

    // ---- weight prep + seed ----
    wc_build<<<(5 * H * H3 + blk - 1) / blk, blk, 0, stream>>>(W, W_ih, Wc);
    tr_mat<<<(H3 * H + blk - 1) / blk, blk, 0, stream>>>(W_hh, Wht, H3, H);
    conv_xT<<<GT_BLOCKS, blk, 0, stream>>>(x, hTb, hh);
    tr_mat<<<(FFD * H + blk - 1) / blk, blk, 0, stream>>>(W1, W1t, FFD, H);
    tr_mat<<<(FFD * FFD + blk - 1) / blk, blk, 0, stream>>>(W2, W2t, FFD, FFD);
    tr_mat<<<(FFD * FFD + blk - 1) / blk, blk, 0, stream>>>(W3, W3t, FFD, FFD);
    tr_mat<<<(NLB * FFD + blk - 1) / blk, blk, 0, stream>>>(Wp, Wpt, NLB, FFD);

    // ---- 5 GGC layers (hTb -> hTa -> hTb -> ...) ----
    const float* hin = hTb;
    float* hout = hTa;
    for (int l = 0; l < 5; ++l) {
        gather_t<<<GA_BLOCKS, blk, 0, stream>>>(hh, rowp, eadj, aggT);
        gru_t<<<GT_BLOCKS, blk, 0, stream>>>(aggT, hin, Wc + (size_t)l * H * H3, Wht,
                                             b_ih, b_hh, hout, hh);
        const float* tmpp = hin; hin = hout; hout = (float*)tmpp;
    }
    // after 5 layers, final state is in hTa (hin points at it)

    // ---- pool ----
    pool_T<<<(NG * 64 + blk - 1) / blk, blk, 0, stream>>>(hin, batch, gbuf);

    // ---- MLP head ----
    dense_t<H, 0, 8><<<((NG / 8) * FFD + blk - 1) / blk, blk, 0, stream>>>(gbuf, W1t, b1, f1, NG, FFD);
    dense_t<FFD, 0, 8><<<((NG / 8) * FFD + blk - 1) / blk, blk, 0, stream>>>(f1, W2t, b2, f2, NG, FFD);
    dense_t<FFD, 0, 8><<<((NG / 8) * FFD + blk - 1) / blk, blk, 0, stream>>>(f2, W3t, b3, f3, NG, FFD);
    dense_t<FFD, 1, 8><<<((NG / 8) * NLB + blk - 1) / blk, blk, 0, stream>>>(f3, Wpt, bp, out, NG, NLB);
}